// Round 6
// baseline (299.458 us; speedup 1.0000x reference)
//
#include <hip/hip_runtime.h>
#include <hip/hip_bf16.h>

#define B_   16
#define CIN  256
#define CO   128
#define HW   4096

typedef __attribute__((ext_vector_type(8))) short short8;
typedef __attribute__((ext_vector_type(4))) float f32x4;

__device__ __forceinline__ short f32_to_bf16_rne(float f) {
    union { float f; unsigned u; } v; v.f = f;
    unsigned u = v.u;
    u += 0x7fffu + ((u >> 16) & 1u);
    return (short)(u >> 16);
}

// ---------------------------------------------------------------------------
// Weight pre-convert: wbf[0][co][ci] = bf16(theta_w), wbf[1][co][ci] = bf16(phi_w)
// ---------------------------------------------------------------------------
__global__ __launch_bounds__(256) void wconv_kernel(
    const float* __restrict__ tw, const float* __restrict__ pw,
    short* __restrict__ wbf)
{
    const int idx = blockIdx.x * 256 + threadIdx.x;     // 0 .. 2*CO*CIN-1
    const float v = (idx < CO * CIN) ? tw[idx] : pw[idx - CO * CIN];
    wbf[idx] = f32_to_bf16_rne(v);
}

// ---------------------------------------------------------------------------
// Projection: out_T[b][i][co] = sum_ci x[b][ci][i] * w[co][ci] + bias[co]
// grid.x = 2048, block = 256 (4 waves). XCD-swizzled: batch b runs on XCD b%8
// so tT/pT lines are dirty-local to the XCD that maxgemm will read them from.
// Weight fragments preloaded to registers; K-loop: global load -> cvt -> LDS
// -> MFMA, dual-buffered, one barrier per chunk.
// ---------------------------------------------------------------------------
__global__ __launch_bounds__(256, 3) void proj_kernel(
    const float* __restrict__ xg, const float* __restrict__ xq,
    const float* __restrict__ tb, const float* __restrict__ pb,
    const short* __restrict__ wbf,
    short* __restrict__ tT, short* __restrict__ pT)
{
    const int n     = blockIdx.x;
    const int xcd   = n & 7;
    const int q     = n >> 3;            // 0..255
    const int b     = xcd + 8 * (q & 1);
    const int r2    = q >> 1;            // 0..127
    const int which = r2 & 1;
    const int itile = r2 >> 1;           // 0..63

    const float* x    = which ? xq : xg;
    const float* bias = which ? pb : tb;
    const short* wb   = wbf + which * CO * CIN;
    short*       out  = which ? pT : tT;

    const int i0   = itile * 64;
    const int tid  = threadIdx.x;
    const int lane = tid & 63;
    const int wv   = tid >> 6;          // wave 0..3 -> co range [wv*32, wv*32+32)
    const int nrow = lane & 15;
    const int quad = lane >> 4;

    const int col4 = tid & 15;          // i group (4 consecutive i) -> coalesced loads
    const int rp   = tid >> 4;          // row-pair index 0..15

    __shared__ short xT[2][64][72];     // [buf][i][ci], 144B rows (16B-divisible)

    f32x4 acc[4][2] = {};               // 4 m-subtiles (i) x 2 n-subtiles (co)

    float bias_v[2];
    bias_v[0] = bias[wv * 32 + 0  + nrow];
    bias_v[1] = bias[wv * 32 + 16 + nrow];

    // ---- preload ALL weight fragments (this wave's 32 co x 256 ci): 64 VGPRs
    short8 wfrag[4][2][2];              // [c4][ks][nt]
    #pragma unroll
    for (int c4 = 0; c4 < 4; c4++)
        #pragma unroll
        for (int ks = 0; ks < 2; ks++)
            #pragma unroll
            for (int nt = 0; nt < 2; nt++)
                wfrag[c4][ks][nt] = *(const short8*)(
                    wb + (wv * 32 + nt * 16 + nrow) * CIN + c4 * 64 + ks * 32 + quad * 8);

    const float* xb = x + (long)b * CIN * HW + i0;

    float4 cva[2], cvb[2];              // pipeline regs

    auto load_chunk = [&](int cc) {
        #pragma unroll
        for (int rr = 0; rr < 2; rr++) {
            const int row = rr * 32 + rp * 2;
            cva[rr] = *(const float4*)(xb + (long)(cc + row)     * HW + col4 * 4);
            cvb[rr] = *(const float4*)(xb + (long)(cc + row + 1) * HW + col4 * 4);
        }
    };
    auto store_chunk = [&](int buf) {
        #pragma unroll
        for (int rr = 0; rr < 2; rr++) {
            const int row = rr * 32 + rp * 2;
            const float* pa  = (const float*)&cva[rr];
            const float* pb2 = (const float*)&cvb[rr];
            #pragma unroll
            for (int k = 0; k < 4; k++) {
                const unsigned lo = (unsigned short)f32_to_bf16_rne(pa[k]);
                const unsigned hi = (unsigned short)f32_to_bf16_rne(pb2[k]);
                *(unsigned*)&xT[buf][col4 * 4 + k][row] = lo | (hi << 16);
            }
        }
    };
    auto mfma_chunk = [&](int c4, int buf) {
        #pragma unroll
        for (int ks = 0; ks < 2; ks++)
            #pragma unroll
            for (int mt = 0; mt < 4; mt++) {
                const short8 a = *(const short8*)&xT[buf][mt * 16 + nrow][ks * 32 + quad * 8];
                acc[mt][0] = __builtin_amdgcn_mfma_f32_16x16x32_bf16(a, wfrag[c4][ks][0], acc[mt][0], 0, 0, 0);
                acc[mt][1] = __builtin_amdgcn_mfma_f32_16x16x32_bf16(a, wfrag[c4][ks][1], acc[mt][1], 0, 0, 0);
            }
    };

    load_chunk(0);
    store_chunk(0);
    #pragma unroll
    for (int c4 = 0; c4 < 4; c4++) {
        __syncthreads();
        if (c4 < 3) load_chunk(c4 * 64 + 64);      // prefetch overlaps MFMA below
        mfma_chunk(c4, c4 & 1);
        if (c4 < 3) store_chunk((c4 + 1) & 1);
    }

    // ---- store: D layout col = lane&15 (co), row = quad*4 + reg (i)
    #pragma unroll
    for (int mt = 0; mt < 4; mt++)
        #pragma unroll
        for (int nt = 0; nt < 2; nt++) {
            const int co = wv * 32 + nt * 16 + nrow;
            #pragma unroll
            for (int r = 0; r < 4; r++) {
                const int il = mt * 16 + quad * 4 + r;
                out[((long)b * HW + i0 + il) * CO + co] =
                    f32_to_bf16_rne(acc[mt][nt][r] + bias_v[nt]);
            }
        }
}

// ---------------------------------------------------------------------------
// Max-GEMM: out[b,i] = sigmoid( max_j ( sum_c tT[b][i][c]*pT[b][j][c] ) / HW )
// grid.x = 256 (1 block/CU), block = 256 (4 waves), XCD-swizzled to match proj
// (p is local-L2 resident: 2 batches x 1 MB per XCD). Wave owns 64 i:
// A fragments loop-invariant in registers (64 VGPR). B fragments loaded
// DIRECTLY global->VGPR, double-buffered (2x32 VGPR): 8 dwordx4 (~200 cyc L2
// latency) issued under 32 MFMA (~620 SIMD-cyc) of the other buffer.
// NO LDS, NO barriers in the main loop -> no bank conflicts, no barrier-drain.
// __launch_bounds__(256,1): up to 512 VGPR so fragments stay in VGPRs
// (R2's 80-VGPR AGPR-staging failure mode).
// ---------------------------------------------------------------------------
__global__ __launch_bounds__(256, 1) void maxgemm_kernel(
    const short* __restrict__ tT, const short* __restrict__ pT,
    float* __restrict__ out)
{
    const int n     = blockIdx.x;
    const int b     = (n & 7) + 8 * ((n >> 3) & 1);
    const int itile = n >> 4;            // 0..15
    const int i0    = itile * 256;
    const int tid   = threadIdx.x;
    const int lane  = tid & 63;
    const int wv    = tid >> 6;
    const int nrow  = lane & 15;
    const int quad  = lane >> 4;

    // ---- loop-invariant A fragments: this wave's 64 i x 128 c (64 VGPRs)
    short8 afrag[4][4];
    {
        const short* tb2 = tT + ((long)b * HW + i0 + wv * 64) * CO;
        #pragma unroll
        for (int mt = 0; mt < 4; mt++)
            #pragma unroll
            for (int ks = 0; ks < 4; ks++)
                afrag[mt][ks] = *(const short8*)(tb2 + (mt * 16 + nrow) * CO + ks * 32 + quad * 8);
    }

    // B base: j = jt*32 + nt*16 + nrow, c = ks*32 + quad*8
    const short* pbase = pT + (long)b * HW * CO + (long)nrow * CO + quad * 8;

    f32x4 vmax[4];
    #pragma unroll
    for (int mt = 0; mt < 4; mt++)
        vmax[mt] = (f32x4){-1e30f, -1e30f, -1e30f, -1e30f};

    short8 bf0[2][4], bf1[2][4];

    auto load_tile = [&](int jt, short8 (*dst)[4]) {   // 32 j x 128 c -> 8 dwordx4
        const short* p2 = pbase + (long)jt * 32 * CO;
        #pragma unroll
        for (int nt = 0; nt < 2; nt++)
            #pragma unroll
            for (int ks = 0; ks < 4; ks++)
                dst[nt][ks] = *(const short8*)(p2 + nt * 16 * CO + ks * 32);
    };
    auto compute = [&](short8 (*bf)[4]) {              // 32 MFMA
        #pragma unroll
        for (int mt = 0; mt < 4; mt++) {
            f32x4 acc0 = {0.f, 0.f, 0.f, 0.f};
            f32x4 acc1 = {0.f, 0.f, 0.f, 0.f};
            #pragma unroll
            for (int ks = 0; ks < 4; ks++) {
                acc0 = __builtin_amdgcn_mfma_f32_16x16x32_bf16(afrag[mt][ks], bf[0][ks], acc0, 0, 0, 0);
                acc1 = __builtin_amdgcn_mfma_f32_16x16x32_bf16(afrag[mt][ks], bf[1][ks], acc1, 0, 0, 0);
            }
            #pragma unroll
            for (int r = 0; r < 4; r++)
                vmax[mt][r] = fmaxf(vmax[mt][r], fmaxf(acc0[r], acc1[r]));
        }
    };

    load_tile(0, bf0);
    for (int jt = 0; jt < 128; jt += 2) {
        load_tile(jt + 1, bf1);                          // prefetch under compute(bf0)
        compute(bf0);
        load_tile((jt + 2 < 128) ? jt + 2 : 0, bf0);     // clamped dummy on last iter
        compute(bf1);
    }

    // ---- reduce max over the 16 j-columns (lane bits 0-3); wave owns its 64 i
    #pragma unroll
    for (int mt = 0; mt < 4; mt++)
        #pragma unroll
        for (int r = 0; r < 4; r++) {
            float v = vmax[mt][r];
            #pragma unroll
            for (int m = 8; m >= 1; m >>= 1)
                v = fmaxf(v, __shfl_xor(v, m, 64));
            vmax[mt][r] = v;
        }

    if (nrow == 0) {
        #pragma unroll
        for (int mt = 0; mt < 4; mt++)
            #pragma unroll
            for (int r = 0; r < 4; r++) {
                const float v = vmax[mt][r] * (1.0f / (float)HW);
                out[(long)b * HW + i0 + wv * 64 + mt * 16 + quad * 4 + r] =
                    1.0f / (1.0f + __expf(-v));
            }
    }
}

extern "C" void kernel_launch(void* const* d_in, const int* in_sizes, int n_in,
                              void* d_out, int out_size, void* d_ws, size_t ws_size,
                              hipStream_t stream) {
    const float* xg = (const float*)d_in[0];
    const float* xq = (const float*)d_in[1];
    const float* tw = (const float*)d_in[2];
    const float* tb = (const float*)d_in[3];
    const float* pw = (const float*)d_in[4];
    const float* pb = (const float*)d_in[5];
    float* out = (float*)d_out;

    short* tT  = (short*)d_ws;                         // [B][HW][CO] bf16, 16.78 MB
    short* pT  = tT + (size_t)B_ * HW * CO;            // [B][HW][CO] bf16, 16.78 MB
    short* wbf = pT + (size_t)B_ * HW * CO;            // [2][CO][CIN] bf16, 131 KB

    wconv_kernel<<<(2 * CO * CIN) / 256, 256, 0, stream>>>(tw, pw, wbf);
    proj_kernel<<<B_ * (HW / 64) * 2, 256, 0, stream>>>(xg, xq, tb, pb, wbf, tT, pT);
    maxgemm_kernel<<<B_ * (HW / 256), 256, 0, stream>>>(tT, pT, out);
}

// Round 7
// 269.928 us; speedup vs baseline: 1.1094x; 1.1094x over previous
//
#include <hip/hip_runtime.h>
#include <hip/hip_bf16.h>

#define B_   16
#define CIN  256
#define CO   128
#define HW   4096

typedef __attribute__((ext_vector_type(8))) short short8;
typedef __attribute__((ext_vector_type(4))) float f32x4;

__device__ __forceinline__ short f32_to_bf16_rne(float f) {
    union { float f; unsigned u; } v; v.f = f;
    unsigned u = v.u;
    u += 0x7fffu + ((u >> 16) & 1u);
    return (short)(u >> 16);
}

// ---------------------------------------------------------------------------
// Weight pre-convert: wbf[0][co][ci] = bf16(theta_w), wbf[1][co][ci] = bf16(phi_w)
// ---------------------------------------------------------------------------
__global__ __launch_bounds__(256) void wconv_kernel(
    const float* __restrict__ tw, const float* __restrict__ pw,
    short* __restrict__ wbf)
{
    const int idx = blockIdx.x * 256 + threadIdx.x;     // 0 .. 2*CO*CIN-1
    const float v = (idx < CO * CIN) ? tw[idx] : pw[idx - CO * CIN];
    wbf[idx] = f32_to_bf16_rne(v);
}

// ---------------------------------------------------------------------------
// Projection: out_T[b][i][co] = sum_ci x[b][ci][i] * w[co][ci] + bias[co]
// grid.x = 2048, block = 256 (4 waves). XCD-swizzled: batch b runs on XCD b%8
// so tT/pT lines are dirty-local to the XCD that maxgemm will read them from.
// Weight fragments preloaded to registers; K-loop: global load -> cvt -> LDS
// -> MFMA, dual-buffered, one barrier per chunk.  (unchanged from R5)
// ---------------------------------------------------------------------------
__global__ __launch_bounds__(256, 3) void proj_kernel(
    const float* __restrict__ xg, const float* __restrict__ xq,
    const float* __restrict__ tb, const float* __restrict__ pb,
    const short* __restrict__ wbf,
    short* __restrict__ tT, short* __restrict__ pT)
{
    const int n     = blockIdx.x;
    const int xcd   = n & 7;
    const int q     = n >> 3;            // 0..255
    const int b     = xcd + 8 * (q & 1);
    const int r2    = q >> 1;            // 0..127
    const int which = r2 & 1;
    const int itile = r2 >> 1;           // 0..63

    const float* x    = which ? xq : xg;
    const float* bias = which ? pb : tb;
    const short* wb   = wbf + which * CO * CIN;
    short*       out  = which ? pT : tT;

    const int i0   = itile * 64;
    const int tid  = threadIdx.x;
    const int lane = tid & 63;
    const int wv   = tid >> 6;          // wave 0..3 -> co range [wv*32, wv*32+32)
    const int nrow = lane & 15;
    const int quad = lane >> 4;

    const int col4 = tid & 15;          // i group (4 consecutive i) -> coalesced loads
    const int rp   = tid >> 4;          // row-pair index 0..15

    __shared__ short xT[2][64][72];     // [buf][i][ci], 144B rows (16B-divisible)

    f32x4 acc[4][2] = {};               // 4 m-subtiles (i) x 2 n-subtiles (co)

    float bias_v[2];
    bias_v[0] = bias[wv * 32 + 0  + nrow];
    bias_v[1] = bias[wv * 32 + 16 + nrow];

    // ---- preload ALL weight fragments (this wave's 32 co x 256 ci): 64 VGPRs
    short8 wfrag[4][2][2];              // [c4][ks][nt]
    #pragma unroll
    for (int c4 = 0; c4 < 4; c4++)
        #pragma unroll
        for (int ks = 0; ks < 2; ks++)
            #pragma unroll
            for (int nt = 0; nt < 2; nt++)
                wfrag[c4][ks][nt] = *(const short8*)(
                    wb + (wv * 32 + nt * 16 + nrow) * CIN + c4 * 64 + ks * 32 + quad * 8);

    const float* xb = x + (long)b * CIN * HW + i0;

    float4 cva[2], cvb[2];              // pipeline regs

    auto load_chunk = [&](int cc) {
        #pragma unroll
        for (int rr = 0; rr < 2; rr++) {
            const int row = rr * 32 + rp * 2;
            cva[rr] = *(const float4*)(xb + (long)(cc + row)     * HW + col4 * 4);
            cvb[rr] = *(const float4*)(xb + (long)(cc + row + 1) * HW + col4 * 4);
        }
    };
    auto store_chunk = [&](int buf) {
        #pragma unroll
        for (int rr = 0; rr < 2; rr++) {
            const int row = rr * 32 + rp * 2;
            const float* pa  = (const float*)&cva[rr];
            const float* pb2 = (const float*)&cvb[rr];
            #pragma unroll
            for (int k = 0; k < 4; k++) {
                const unsigned lo = (unsigned short)f32_to_bf16_rne(pa[k]);
                const unsigned hi = (unsigned short)f32_to_bf16_rne(pb2[k]);
                *(unsigned*)&xT[buf][col4 * 4 + k][row] = lo | (hi << 16);
            }
        }
    };
    auto mfma_chunk = [&](int c4, int buf) {
        #pragma unroll
        for (int ks = 0; ks < 2; ks++)
            #pragma unroll
            for (int mt = 0; mt < 4; mt++) {
                const short8 a = *(const short8*)&xT[buf][mt * 16 + nrow][ks * 32 + quad * 8];
                acc[mt][0] = __builtin_amdgcn_mfma_f32_16x16x32_bf16(a, wfrag[c4][ks][0], acc[mt][0], 0, 0, 0);
                acc[mt][1] = __builtin_amdgcn_mfma_f32_16x16x32_bf16(a, wfrag[c4][ks][1], acc[mt][1], 0, 0, 0);
            }
    };

    load_chunk(0);
    store_chunk(0);
    #pragma unroll
    for (int c4 = 0; c4 < 4; c4++) {
        __syncthreads();
        if (c4 < 3) load_chunk(c4 * 64 + 64);      // prefetch overlaps MFMA below
        mfma_chunk(c4, c4 & 1);
        if (c4 < 3) store_chunk((c4 + 1) & 1);
    }

    // ---- store: D layout col = lane&15 (co), row = quad*4 + reg (i)
    #pragma unroll
    for (int mt = 0; mt < 4; mt++)
        #pragma unroll
        for (int nt = 0; nt < 2; nt++) {
            const int co = wv * 32 + nt * 16 + nrow;
            #pragma unroll
            for (int r = 0; r < 4; r++) {
                const int il = mt * 16 + quad * 4 + r;
                out[((long)b * HW + i0 + il) * CO + co] =
                    f32_to_bf16_rne(acc[mt][nt][r] + bias_v[nt]);
            }
        }
}

// ---------------------------------------------------------------------------
// Max-GEMM: out[b,i] = sigmoid( max_j ( sum_c tT[b][i][c]*pT[b][j][c] ) / HW )
// grid.x = 512 (2 blocks/CU), block = 256 (4 waves), XCD-swizzled.
// Block owns 128 i. Every wave holds A for ALL 128 i (8x4 short8 = 128 VGPR,
// loop-invariant; AGPR placement harmless -- MFMA reads AGPR A-operands).
// Waves SPLIT j: wave w computes j-slice [wv*16, wv*16+16) of each staged
// 64-j LDS tile -> only 4 ds_read_b128 + 32 MFMA per wave per jt.
// XOR-swizzled chunks (verified in R5) keep both LDS writes and reads at the
// free 2-way aliasing level. 2 waves/SIMD hide ds latency + barrier skew.
// Cross-wave j-max merged through smax at the end.
// ---------------------------------------------------------------------------
__global__ __launch_bounds__(256, 2) void maxgemm_kernel(
    const short* __restrict__ tT, const short* __restrict__ pT,
    float* __restrict__ out)
{
    const int n     = blockIdx.x;
    const int xcd   = n & 7;
    const int q     = n >> 3;            // 0..63
    const int b     = xcd + 8 * (q & 1);
    const int itile = q >> 1;            // 0..31
    const int i0    = itile * 128;
    const int tid   = threadIdx.x;
    const int lane  = tid & 63;
    const int wv    = tid >> 6;
    const int nrow  = lane & 15;
    const int quad  = lane >> 4;

    __shared__ short bT[2][64][128];     // 32 KB, unpadded, XOR-swizzled chunks
    __shared__ float smax[128][4];

    // ---- loop-invariant A fragments: ALL 128 i x 128 c (128 VGPR/AGPR)
    short8 afrag[8][4];
    {
        const short* tb2 = tT + ((long)b * HW + i0) * CO;
        #pragma unroll
        for (int mt = 0; mt < 8; mt++)
            #pragma unroll
            for (int ks = 0; ks < 4; ks++)
                afrag[mt][ks] = *(const short8*)(tb2 + (mt * 16 + nrow) * CO + ks * 32 + quad * 8);
    }

    const short* pbb = pT + (long)b * HW * CO;
    const int sc8 = tid & 15;            // 16B chunk within row
    const int sj0 = tid >> 4;            // 0..15

    short8 sreg[4];
    auto stage_load = [&](int jt) {      // global -> regs (coalesced 256B segs)
        const short* src = pbb + (long)jt * 64 * CO;
        #pragma unroll
        for (int r = 0; r < 4; r++)
            sreg[r] = *(const short8*)(src + (sj0 + r * 16) * CO + sc8 * 8);
    };
    auto stage_write = [&](int buf) {    // regs -> LDS, swizzled chunk
        #pragma unroll
        for (int r = 0; r < 4; r++) {
            const int j  = sj0 + r * 16;
            const int c8 = sc8 ^ (j & 7);
            *(short8*)&bT[buf][j][c8 * 8] = sreg[r];
        }
    };

    f32x4 vmax[8];
    #pragma unroll
    for (int mt = 0; mt < 8; mt++)
        vmax[mt] = (f32x4){-1e30f, -1e30f, -1e30f, -1e30f};

    auto compute = [&](int buf) {
        short8 bf[4];
        const int j = wv * 16 + nrow;    // this wave's j-slice
        #pragma unroll
        for (int ks = 0; ks < 4; ks++) {
            const int c8 = (ks * 4 + quad) ^ (j & 7);
            bf[ks] = *(const short8*)&bT[buf][j][c8 * 8];
        }
        #pragma unroll
        for (int mt = 0; mt < 8; mt++) {
            f32x4 acc = {0.f, 0.f, 0.f, 0.f};
            #pragma unroll
            for (int ks = 0; ks < 4; ks++)
                acc = __builtin_amdgcn_mfma_f32_16x16x32_bf16(afrag[mt][ks], bf[ks], acc, 0, 0, 0);
            #pragma unroll
            for (int r = 0; r < 4; r++)
                vmax[mt][r] = fmaxf(vmax[mt][r], acc[r]);
        }
    };

    stage_load(0);
    stage_write(0);
    for (int jt = 0; jt < 64; jt++) {
        __syncthreads();
        if (jt < 63) stage_load(jt + 1);     // prefetch overlaps MFMA below
        compute(jt & 1);
        if (jt < 63) stage_write((jt + 1) & 1);
    }

    // ---- reduce max over this wave's 16 j-columns (lane bits 0-3)
    #pragma unroll
    for (int mt = 0; mt < 8; mt++)
        #pragma unroll
        for (int r = 0; r < 4; r++) {
            float v = vmax[mt][r];
            #pragma unroll
            for (int m = 8; m >= 1; m >>= 1)
                v = fmaxf(v, __shfl_xor(v, m, 64));
            vmax[mt][r] = v;
        }

    // ---- cross-wave merge: smax[i][wv]
    if (nrow == 0) {
        #pragma unroll
        for (int mt = 0; mt < 8; mt++)
            #pragma unroll
            for (int r = 0; r < 4; r++)
                smax[mt * 16 + quad * 4 + r][wv] = vmax[mt][r];
    }
    __syncthreads();

    if (tid < 128) {
        float v = fmaxf(fmaxf(smax[tid][0], smax[tid][1]),
                        fmaxf(smax[tid][2], smax[tid][3]));
        v *= (1.0f / (float)HW);
        out[(long)b * HW + i0 + tid] = 1.0f / (1.0f + __expf(-v));
    }
}

extern "C" void kernel_launch(void* const* d_in, const int* in_sizes, int n_in,
                              void* d_out, int out_size, void* d_ws, size_t ws_size,
                              hipStream_t stream) {
    const float* xg = (const float*)d_in[0];
    const float* xq = (const float*)d_in[1];
    const float* tw = (const float*)d_in[2];
    const float* tb = (const float*)d_in[3];
    const float* pw = (const float*)d_in[4];
    const float* pb = (const float*)d_in[5];
    float* out = (float*)d_out;

    short* tT  = (short*)d_ws;                         // [B][HW][CO] bf16, 16.78 MB
    short* pT  = tT + (size_t)B_ * HW * CO;            // [B][HW][CO] bf16, 16.78 MB
    short* wbf = pT + (size_t)B_ * HW * CO;            // [2][CO][CIN] bf16, 131 KB

    wconv_kernel<<<(2 * CO * CIN) / 256, 256, 0, stream>>>(tw, pw, wbf);
    proj_kernel<<<B_ * (HW / 64) * 2, 256, 0, stream>>>(xg, xq, tb, pb, wbf, tT, pT);
    maxgemm_kernel<<<B_ * (HW / 128), 256, 0, stream>>>(tT, pT, out);
}

// Round 9
// 266.674 us; speedup vs baseline: 1.1229x; 1.0122x over previous
//
#include <hip/hip_runtime.h>
#include <hip/hip_bf16.h>

#define B_   16
#define CIN  256
#define CO   128
#define HW   4096

typedef __attribute__((ext_vector_type(8))) short short8;
typedef __attribute__((ext_vector_type(4))) float f32x4;

__device__ __forceinline__ unsigned bf16_rne_u16(float f) {
    union { float f; unsigned u; } v; v.f = f;
    return (v.u + 0x7fffu + ((v.u >> 16) & 1u)) >> 16;
}
__device__ __forceinline__ unsigned pack_bf16x2(float lo, float hi) {
    return bf16_rne_u16(lo) | (bf16_rne_u16(hi) << 16);
}
__device__ __forceinline__ short f32_to_bf16_rne(float f) {
    return (short)bf16_rne_u16(f);
}

#define AS1(p) ((const __attribute__((address_space(1))) unsigned*)(p))
#define AS3(p) ((__attribute__((address_space(3))) unsigned*)(p))

// ---------------------------------------------------------------------------
// Projection: out_T[b][i][co] = sum_ci x[b][ci][i] * w[co][ci] + bias[co]
// grid.x = 2048, block = 256 (4 waves), XCD-swizzled (batch -> XCD b%8).
// BARRIER-FREE, NO LDS: each lane loads its MFMA A-fragment elements directly
// from global x (two 32-load half-chunks in flight -> 64 outstanding loads),
// converts f32->bf16 in-register, MFMAs against register-resident weights.
// pT stores are chunk-XOR-swizzled (chunk' = chunk ^ (i&7)) so maxgemm's
// lane-linear LDS DMA yields conflict-floor ds_read_b128.
// ---------------------------------------------------------------------------
__global__ __launch_bounds__(256, 2) void proj_kernel(
    const float* __restrict__ xg, const float* __restrict__ xq,
    const float* __restrict__ tw, const float* __restrict__ tb,
    const float* __restrict__ pw, const float* __restrict__ pb,
    short* __restrict__ tT, short* __restrict__ pT)
{
    const int n     = blockIdx.x;
    const int xcd   = n & 7;
    const int q     = n >> 3;            // 0..255
    const int b     = xcd + 8 * (q & 1);
    const int r2    = q >> 1;            // 0..127
    const int which = r2 & 1;
    const int itile = r2 >> 1;           // 0..63

    const float* x    = which ? xq : xg;
    const float* wsrc = which ? pw : tw;
    const float* bias = which ? pb : tb;
    short*       out  = which ? pT : tT;

    const int i0   = itile * 64;
    const int tid  = threadIdx.x;
    const int lane = tid & 63;
    const int wv   = tid >> 6;          // wave 0..3 -> co range [wv*32, wv*32+32)
    const int nrow = lane & 15;
    const int quad = lane >> 4;

    // ---- prologue: weights fp32 -> bf16 fragments in regs (64 VGPR)
    short8 wfrag[4][2][2];              // [c4][ks][nt]
    #pragma unroll
    for (int c4 = 0; c4 < 4; c4++)
        #pragma unroll
        for (int ks = 0; ks < 2; ks++)
            #pragma unroll
            for (int nt = 0; nt < 2; nt++) {
                const float* wp = wsrc + (wv * 32 + nt * 16 + nrow) * CIN
                                       + c4 * 64 + ks * 32 + quad * 8;
                const float4 w0 = ((const float4*)wp)[0];
                const float4 w1 = ((const float4*)wp)[1];
                union { short8 s; unsigned u[4]; } t;
                t.u[0] = pack_bf16x2(w0.x, w0.y);
                t.u[1] = pack_bf16x2(w0.z, w0.w);
                t.u[2] = pack_bf16x2(w1.x, w1.y);
                t.u[3] = pack_bf16x2(w1.z, w1.w);
                wfrag[c4][ks][nt] = t.s;
            }

    float bias_v[2];
    bias_v[0] = bias[wv * 32 + 0  + nrow];
    bias_v[1] = bias[wv * 32 + 16 + nrow];

    f32x4 acc[4][2] = {};               // [mt][nt]

    const float* xb = x + (long)b * CIN * HW + i0 + nrow;

    float xs0[32], xs1[32];             // two half-chunk staging groups

    auto load_group = [&](int hc, float* xs) {   // hc = c4*2+ks : 32 dwords
        const float* xb2 = xb + (long)(hc * 32 + quad * 8) * HW;
        #pragma unroll
        for (int j = 0; j < 8; j++)
            #pragma unroll
            for (int mt = 0; mt < 4; mt++)
                xs[mt * 8 + j] = xb2[(long)j * HW + mt * 16];
    };

    load_group(0, xs0);
    load_group(1, xs1);
    #pragma unroll
    for (int hc = 0; hc < 8; hc++) {
        float* cur = (hc & 1) ? xs1 : xs0;
        short8 af[4];
        #pragma unroll
        for (int mt = 0; mt < 4; mt++) {
            union { short8 s; unsigned u[4]; } t;
            #pragma unroll
            for (int e = 0; e < 4; e++)
                t.u[e] = pack_bf16x2(cur[mt * 8 + 2 * e], cur[mt * 8 + 2 * e + 1]);
            af[mt] = t.s;
        }
        if (hc < 6) load_group(hc + 2, cur);     // refill staging, stays in flight
        const int c4 = hc >> 1, ks = hc & 1;
        #pragma unroll
        for (int mt = 0; mt < 4; mt++) {
            acc[mt][0] = __builtin_amdgcn_mfma_f32_16x16x32_bf16(af[mt], wfrag[c4][ks][0], acc[mt][0], 0, 0, 0);
            acc[mt][1] = __builtin_amdgcn_mfma_f32_16x16x32_bf16(af[mt], wfrag[c4][ks][1], acc[mt][1], 0, 0, 0);
        }
    }

    // ---- store: D layout col = nrow (co), row = quad*4 + r (i)
    #pragma unroll
    for (int mt = 0; mt < 4; mt++)
        #pragma unroll
        for (int nt = 0; nt < 2; nt++) {
            const int co = wv * 32 + nt * 16 + nrow;
            #pragma unroll
            for (int r = 0; r < 4; r++) {
                const int il = mt * 16 + quad * 4 + r;
                int col = co;
                if (which)  // pT: pre-bake maxgemm's LDS XOR swizzle
                    col = (((co >> 3) ^ (il & 7)) << 3) | (co & 7);
                out[((long)b * HW + i0 + il) * CO + col] =
                    f32_to_bf16_rne(acc[mt][nt][r] + bias_v[nt]);
            }
        }
}

// ---------------------------------------------------------------------------
// Max-GEMM: out[b,i] = sigmoid( max_j ( sum_c tT[b][i][c]*pT[b][j][c] ) / HW )
// grid.x = 512 (2 blocks/CU), block = 256 (4 waves), XCD-swizzled.
// Block owns 128 i (A frags for all 128 i in regs/AGPRs, loop-invariant).
// Each wave owns j-slice [wv*32, wv*32+32) of every 128-j tile and a PRIVATE
// double-buffered LDS region filled via global_load_lds (lane-linear 16B DMA).
// NO barriers in the loop: sync is s_waitcnt vmcnt(8) -- the next tile's 8
// DMAs stay in flight across the wait (AITER-style pipeline).
// pT is pre-swizzled by proj so ds_read_b128 sits at the bank floor.
// ---------------------------------------------------------------------------
__global__ __launch_bounds__(256, 2) void maxgemm_kernel(
    const short* __restrict__ tT, const short* __restrict__ pT,
    float* __restrict__ out)
{
    const int n     = blockIdx.x;
    const int b     = (n & 7) + 8 * ((n >> 3) & 1);
    const int itile = n >> 4;            // 0..31
    const int i0    = itile * 128;
    const int tid   = threadIdx.x;
    const int lane  = tid & 63;
    const int wv    = tid >> 6;
    const int nrow  = lane & 15;
    const int quad  = lane >> 4;

    __shared__ short bT[4][2][32][128];  // [wave][buf][row][c] = 64 KB
    __shared__ float smax[128][4];

    // ---- loop-invariant A fragments: 128 i x 128 c (128 regs, AGPR-friendly)
    short8 afrag[8][4];
    {
        const short* tb2 = tT + ((long)b * HW + i0) * CO;
        #pragma unroll
        for (int mt = 0; mt < 8; mt++)
            #pragma unroll
            for (int ks = 0; ks < 4; ks++)
                afrag[mt][ks] = *(const short8*)(tb2 + (mt * 16 + nrow) * CO + ks * 32 + quad * 8);
    }

    // ---- DMA: wave w stages rows [wv*32, wv*32+32) of each 128-j tile.
    // One dma4 = 4 x (64 lanes x 16B) = 16 rows; literal offsets (ICE req).
    unsigned long g0 = (unsigned long)(pT + (long)b * HW * CO + (long)(wv * 32) * CO)
                     + (unsigned)lane * 16;

    auto dma4 = [&](unsigned long gA, short* lds) {
        __builtin_amdgcn_global_load_lds(AS1(gA), AS3(lds),        16, 0,    0);
        __builtin_amdgcn_global_load_lds(AS1(gA), AS3(lds + 512),  16, 1024, 0);
        __builtin_amdgcn_global_load_lds(AS1(gA), AS3(lds + 1024), 16, 2048, 0);
        __builtin_amdgcn_global_load_lds(AS1(gA), AS3(lds + 1536), 16, 3072, 0);
    };
    auto dma_tile = [&](unsigned long gA, int buf) {   // 32 rows = 8192 B
        dma4(gA,        &bT[wv][buf][0][0]);
        dma4(gA + 4096, &bT[wv][buf][16][0]);
    };

    unsigned long gcur = g0;
    dma_tile(gcur, 0);
    asm volatile("" ::: "memory");
    gcur += 32768;
    dma_tile(gcur, 1);
    asm volatile("" ::: "memory");
    gcur += 32768;

    f32x4 vmax[8];
    #pragma unroll
    for (int mt = 0; mt < 8; mt++)
        vmax[mt] = (f32x4){-1e30f, -1e30f, -1e30f, -1e30f};

    const int swz = nrow & 7;

    for (int k = 0; k < 32; k++) {
        asm volatile("s_waitcnt vmcnt(8)" ::: "memory");   // buf(k&1) landed; next 8 fly
        const int buf = k & 1;

        short8 bf[2][4];
        #pragma unroll
        for (int nt = 0; nt < 2; nt++)
            #pragma unroll
            for (int ks = 0; ks < 4; ks++)
                bf[nt][ks] = *(const short8*)&bT[wv][buf][nt * 16 + nrow][(((ks * 4 + quad) ^ swz) << 3)];

        #pragma unroll
        for (int mt = 0; mt < 8; mt++) {
            f32x4 a0 = {0.f, 0.f, 0.f, 0.f};
            f32x4 a1 = {0.f, 0.f, 0.f, 0.f};
            #pragma unroll
            for (int ks = 0; ks < 4; ks++) {
                a0 = __builtin_amdgcn_mfma_f32_16x16x32_bf16(afrag[mt][ks], bf[0][ks], a0, 0, 0, 0);
                a1 = __builtin_amdgcn_mfma_f32_16x16x32_bf16(afrag[mt][ks], bf[1][ks], a1, 0, 0, 0);
            }
            #pragma unroll
            for (int r = 0; r < 4; r++)
                vmax[mt][r] = fmaxf(vmax[mt][r], fmaxf(a0[r], a1[r]));
        }

        asm volatile("s_waitcnt lgkmcnt(0)" ::: "memory"); // ds_reads of buf done
        const unsigned long gi = (k + 2 >= 32) ? (gcur - 32UL * 32768UL) : gcur; // tail: dummy refill
        dma_tile(gi, buf);
        asm volatile("" ::: "memory");
        gcur += 32768;
    }

    // ---- reduce max over this wave's 16 j-columns (lane bits 0-3)
    #pragma unroll
    for (int mt = 0; mt < 8; mt++)
        #pragma unroll
        for (int r = 0; r < 4; r++) {
            float v = vmax[mt][r];
            #pragma unroll
            for (int m = 8; m >= 1; m >>= 1)
                v = fmaxf(v, __shfl_xor(v, m, 64));
            vmax[mt][r] = v;
        }

    // ---- cross-wave merge (waves covered disjoint j)
    if (nrow == 0) {
        #pragma unroll
        for (int mt = 0; mt < 8; mt++)
            #pragma unroll
            for (int r = 0; r < 4; r++)
                smax[mt * 16 + quad * 4 + r][wv] = vmax[mt][r];
    }
    __syncthreads();

    if (tid < 128) {
        float v = fmaxf(fmaxf(smax[tid][0], smax[tid][1]),
                        fmaxf(smax[tid][2], smax[tid][3]));
        v *= (1.0f / (float)HW);
        out[(long)b * HW + i0 + tid] = 1.0f / (1.0f + __expf(-v));
    }
}

extern "C" void kernel_launch(void* const* d_in, const int* in_sizes, int n_in,
                              void* d_out, int out_size, void* d_ws, size_t ws_size,
                              hipStream_t stream) {
    const float* xg = (const float*)d_in[0];
    const float* xq = (const float*)d_in[1];
    const float* tw = (const float*)d_in[2];
    const float* tb = (const float*)d_in[3];
    const float* pw = (const float*)d_in[4];
    const float* pb = (const float*)d_in[5];
    float* out = (float*)d_out;

    short* tT = (short*)d_ws;                       // [B][HW][CO] bf16, 16.78 MB
    short* pT = tT + (size_t)B_ * HW * CO;          // [B][HW][CO] bf16 (swizzled), 16.78 MB

    proj_kernel<<<B_ * (HW / 64) * 2, 256, 0, stream>>>(xg, xq, tw, tb, pw, pb, tT, pT);
    maxgemm_kernel<<<B_ * (HW / 128), 256, 0, stream>>>(tT, pT, out);
}